// Round 5
// baseline (57.579 us; speedup 1.0000x reference)
//
#include <hip/hip_runtime.h>

#define BB 2
#define CC 64
#define CI 32
#define NPIX 9216   // 96*96
#define TN 128      // pixels per block tile
#define NCH 72      // NPIX / TN chunks per batch
#define NBLK (BB * NCH)  // 144 blocks

// ---------------------------------------------------------------------------
// k1: S += X_tile X_tile^T (fp32 HW atomics), r += X_tile @ 1
// Full 128-px tile staged via coalesced float4 loads, transposed in LDS,
// single __syncthreads, then one 128-iteration register-tiled MAC loop.
// ---------------------------------------------------------------------------
__global__ __launch_bounds__(256) void k1_stats(
    const float* __restrict__ x, float* __restrict__ Sf,
    float* __restrict__ rf) {
  __shared__ float xt[TN][CC + 4];  // [px][ch], 68-float rows (bank-safe)
  const int t = threadIdx.x;
  const int blk = blockIdx.x;
  const int batch = blk / NCH;
  const int chk = blk - batch * NCH;
  const int n0 = chk * TN;
  const float* __restrict__ X = x + (size_t)batch * CC * NPIX + n0;

  // ---- load + transpose + per-channel row-sum partials
  const int cg = t >> 5;        // 0..7: channel within each 8-group
  const int p4 = (t & 31) * 4;  // pixel group (float4)
  float rsum[8];
#pragma unroll
  for (int c8 = 0; c8 < 8; ++c8) {
    const int c = c8 * 8 + cg;
    const float4 v =
        *reinterpret_cast<const float4*>(&X[(size_t)c * NPIX + p4]);
    xt[p4 + 0][c] = v.x;
    xt[p4 + 1][c] = v.y;
    xt[p4 + 2][c] = v.z;
    xt[p4 + 3][c] = v.w;
    rsum[c8] = v.x + v.y + v.z + v.w;
  }
  __syncthreads();

  // ---- r: reduce across the 32 pixel-lanes, one atomic per (block, channel)
#pragma unroll
  for (int c8 = 0; c8 < 8; ++c8) {
    float v = rsum[c8];
    v += __shfl_down(v, 16, 32);
    v += __shfl_down(v, 8, 32);
    v += __shfl_down(v, 4, 32);
    v += __shfl_down(v, 2, 32);
    v += __shfl_down(v, 1, 32);
    if ((t & 31) == 0) unsafeAtomicAdd(&rf[batch * CC + c8 * 8 + cg], v);
  }

  // ---- S: 4x4 register tile per thread over 128 pixels
  const int i0 = (t >> 4) * 4;
  const int j0 = (t & 15) * 4;
  float acc[4][4] = {};
#pragma unroll 4
  for (int n = 0; n < TN; ++n) {
    const float4 av = *reinterpret_cast<const float4*>(&xt[n][i0]);
    const float4 bv = *reinterpret_cast<const float4*>(&xt[n][j0]);
    const float a[4] = {av.x, av.y, av.z, av.w};
    const float b[4] = {bv.x, bv.y, bv.z, bv.w};
#pragma unroll
    for (int ii = 0; ii < 4; ++ii)
#pragma unroll
      for (int jj = 0; jj < 4; ++jj) acc[ii][jj] += a[ii] * b[jj];
  }

  float* Sb = Sf + (size_t)batch * CC * CC;
#pragma unroll
  for (int ii = 0; ii < 4; ++ii)
#pragma unroll
    for (int jj = 0; jj < 4; ++jj)
      unsafeAtomicAdd(&Sb[(i0 + ii) * CC + j0 + jj], acc[ii][jj]);
}

// ---------------------------------------------------------------------------
// k2: per-block redundant tiny algebra -> W_b, b_b in LDS, then apply
//     Z = X + W_b X + b_b on this block's 128-px tile.
// ---------------------------------------------------------------------------
struct Alg {
  float S[CC][CC + 1];
  float Gt[CC][CI + 1];  // gw transposed
  float A[CI][CC + 1];   // pw @ S
  float M[CI][CI + 1];
  float T1[CI][CC + 1];  // (M^T tw)
  float r[CC];
  float u[CI], v[CI], t2[CI];
};

struct Smem {
  union U {
    Alg alg;            // algebra scratch (46.6 KB)
    float xt[CC][TN];   // apply-phase x tile (32.8 KB)
  } u;
  float Wt[CC][68];     // Wt[inch][outch], persists algebra -> apply
  float bl[CC];
};

__global__ __launch_bounds__(256) void k2_apply(
    const float* __restrict__ x, const float* __restrict__ tw,
    const float* __restrict__ tb, const float* __restrict__ pw,
    const float* __restrict__ pb, const float* __restrict__ gw,
    const float* __restrict__ gb, const float* __restrict__ rw,
    const float* __restrict__ rb, float* __restrict__ z,
    const float* __restrict__ Sf, const float* __restrict__ rf) {
  __shared__ __align__(16) Smem sm;
  const int t = threadIdx.x;
  const int blk = blockIdx.x;
  const int batch = blk / NCH;
  const int chk = blk - batch * NCH;

  // ---- algebra (every block, redundantly; operands L1/L2-hot)
  {
    Alg& a = sm.u.alg;
    const float* Sb = Sf + (size_t)batch * CC * CC;
    for (int idx = t; idx < CC * CC; idx += 256)
      a.S[idx >> 6][idx & 63] = Sb[idx];
    for (int idx = t; idx < CI * CC; idx += 256) {
      int c = idx >> 6, j = idx & 63;
      a.Gt[j][c] = gw[idx];
    }
    if (t < CC) a.r[t] = rf[batch * CC + t];
    __syncthreads();

    if (t < CI) {
      float s = 0.f;
      for (int i = 0; i < CC; ++i) s += gw[t * CC + i] * a.r[i];
      a.u[t] = s;
    } else if (t < 2 * CI) {
      const int k = t - CI;
      float s = 0.f;
      for (int i = 0; i < CC; ++i) s += pw[k * CC + i] * a.r[i];
      a.v[k] = s;
    }
    // A[k][j] = sum_i pw[k][i] S[i][j]
    for (int o = t; o < CI * CC; o += 256) {
      const int k = o >> 6, j = o & 63;
      float s = 0.f;
      for (int i = 0; i < CC; ++i) s += pw[k * CC + i] * a.S[i][j];
      a.A[k][j] = s;
    }
    __syncthreads();

    // M[k][c] = sum_j A[k][j] Gt[j][c] + v[k] gb[c] + pb[k] u[c] + N pb[k] gb[c]
    for (int o = t; o < CI * CI; o += 256) {
      const int k = o >> 5, c = o & 31;
      float s = 0.f;
      for (int j = 0; j < CC; ++j) s += a.A[k][j] * a.Gt[j][c];
      s += a.v[k] * gb[c] + pb[k] * a.u[c] + (float)NPIX * pb[k] * gb[c];
      a.M[k][c] = s;
    }
    __syncthreads();

    // T1[c][j] = sum_k M[k][c] tw[k][j];  t2[c] = sum_k M[k][c] tb[k]
    for (int o = t; o < CI * CC; o += 256) {
      const int c = o >> 6, j = o & 63;
      float s = 0.f;
      for (int k = 0; k < CI; ++k) s += a.M[k][c] * tw[k * CC + j];
      a.T1[c][j] = s;
    }
    if (t < CI) {
      float s = 0.f;
      for (int k = 0; k < CI; ++k) s += a.M[k][t] * tb[k];
      a.t2[t] = s;
    }
    __syncthreads();

    const float invN = 1.0f / (float)NPIX;
    // Wt[j][oc] = invN * sum_c rw[oc][c] T1[c][j]   (transposed for apply)
    for (int o = t; o < CC * CC; o += 256) {
      const int oc = o >> 6, j = o & 63;
      float s = 0.f;
      for (int c = 0; c < CI; ++c) s += rw[oc * CI + c] * a.T1[c][j];
      sm.Wt[j][oc] = s * invN;
    }
    if (t < CC) {
      float s = 0.f;
      for (int c = 0; c < CI; ++c) s += rw[t * CI + c] * a.t2[c];
      sm.bl[t] = s * invN + rb[t];
    }
  }
  __syncthreads();

  // ---- apply: Z = X + W_b X + b_b for this block's 128-px tile
  {
    const int n0 = chk * TN;
    const float* __restrict__ X = x + (size_t)batch * CC * NPIX;
    float* __restrict__ Z = z + (size_t)batch * CC * NPIX;

    for (int idx = t; idx < CC * TN / 4; idx += 256) {
      const int k = idx >> 5;             // channel (128/4 = 32 groups)
      const int n = (idx & 31) * 4;       // pixel group
      *reinterpret_cast<float4*>(&sm.u.xt[k][n]) =
          *reinterpret_cast<const float4*>(&X[(size_t)k * NPIX + n0 + n]);
    }
    __syncthreads();

    const int c0 = (t >> 5) * 8;
    const int m0 = (t & 31) * 4;
    float acc[8][4] = {};
#pragma unroll 4
    for (int k = 0; k < CC; ++k) {
      const float4 xv = *reinterpret_cast<const float4*>(&sm.u.xt[k][m0]);
      const float4 w0 = *reinterpret_cast<const float4*>(&sm.Wt[k][c0]);
      const float4 w1 = *reinterpret_cast<const float4*>(&sm.Wt[k][c0 + 4]);
      const float xa[4] = {xv.x, xv.y, xv.z, xv.w};
      const float wa[8] = {w0.x, w0.y, w0.z, w0.w, w1.x, w1.y, w1.z, w1.w};
#pragma unroll
      for (int cc = 0; cc < 8; ++cc)
#pragma unroll
        for (int nn = 0; nn < 4; ++nn) acc[cc][nn] += wa[cc] * xa[nn];
    }

#pragma unroll
    for (int cc = 0; cc < 8; ++cc) {
      const int c = c0 + cc;
      const float4 xr = *reinterpret_cast<const float4*>(&sm.u.xt[c][m0]);
      const float bb2 = sm.bl[c];
      float4 o;
      o.x = acc[cc][0] + xr.x + bb2;
      o.y = acc[cc][1] + xr.y + bb2;
      o.z = acc[cc][2] + xr.z + bb2;
      o.w = acc[cc][3] + xr.w + bb2;
      *reinterpret_cast<float4*>(&Z[(size_t)c * NPIX + n0 + m0]) = o;
    }
  }
}

extern "C" void kernel_launch(void* const* d_in, const int* in_sizes, int n_in,
                              void* d_out, int out_size, void* d_ws,
                              size_t ws_size, hipStream_t stream) {
  (void)in_sizes; (void)n_in; (void)out_size; (void)ws_size;
  const float* x  = (const float*)d_in[0];
  const float* tw = (const float*)d_in[1];
  const float* tb = (const float*)d_in[2];
  const float* pw = (const float*)d_in[3];
  const float* pb = (const float*)d_in[4];
  const float* gw = (const float*)d_in[5];
  const float* gb = (const float*)d_in[6];
  const float* rw = (const float*)d_in[7];
  const float* rb = (const float*)d_in[8];
  float* z = (float*)d_out;

  float* Sf = (float*)d_ws;                  // BB*4096
  float* rf = Sf + (size_t)BB * CC * CC;     // BB*64

  const size_t zero_bytes = ((size_t)BB * (CC * CC + CC)) * sizeof(float);
  hipMemsetAsync(d_ws, 0, zero_bytes, stream);

  hipLaunchKernelGGL(k1_stats, dim3(NBLK), dim3(256), 0, stream, x, Sf, rf);
  hipLaunchKernelGGL(k2_apply, dim3(NBLK), dim3(256), 0, stream,
                     x, tw, tb, pw, pb, gw, gb, rw, rb, z, Sf, rf);
}

// Round 6
// 55.718 us; speedup vs baseline: 1.0334x; 1.0334x over previous
//
#include <hip/hip_runtime.h>

#define BB 2
#define CC 64
#define CI 32
#define NPIX 9216            // 96*96

#define K1_PX 32             // pixels per k1 block
#define K1_CHUNKS (NPIX / K1_PX)      // 288 per batch
#define K1_BLOCKS (BB * K1_CHUNKS)    // 576

#define KR_ELEMS 64
#define KR_BLOCKS_PER_B (CC * CC / KR_ELEMS)  // 64
#define KR_BLOCKS (BB * KR_BLOCKS_PER_B)      // 128
#define KSLICE (K1_CHUNKS / 4)        // 72 partials per reduction slice

#define K3_PX 64             // pixels per k3 block
#define K3_CHUNKS (NPIX / K3_PX)      // 144 per batch
#define K3_BLOCKS (BB * K3_CHUNKS)    // 288

// ---------------------------------------------------------------------------
// k1: per-(batch,32px-chunk) partials  Sp = X_c X_c^T (64x64), rp = X_c @ 1
// Plain stores, no atomics. 576 blocks -> ~2.2 blocks/CU.
// ---------------------------------------------------------------------------
__global__ __launch_bounds__(256) void k1_partials(
    const float* __restrict__ x, float* __restrict__ Spart,
    float* __restrict__ rpart) {
  __shared__ float xt[K1_PX][CC + 4];  // [px][ch], padded
  const int t = threadIdx.x;
  const int blk = blockIdx.x;
  const int batch = blk / K1_CHUNKS;
  const int chk = blk - batch * K1_CHUNKS;
  const int n0 = chk * K1_PX;
  const float* __restrict__ X = x + (size_t)batch * CC * NPIX + n0;

  // stage + transpose: 512 float4s, 2 per thread, 8 channels/wave coalesced
#pragma unroll
  for (int h = 0; h < 2; ++h) {
    const int c = (t >> 3) + 32 * h;
    const int p = (t & 7) * 4;
    const float4 v = *reinterpret_cast<const float4*>(&X[(size_t)c * NPIX + p]);
    xt[p + 0][c] = v.x;
    xt[p + 1][c] = v.y;
    xt[p + 2][c] = v.z;
    xt[p + 3][c] = v.w;
  }
  __syncthreads();

  // r partial: threads 0..63 each sum their channel's 32 pixels
  if (t < CC) {
    float s = 0.f;
#pragma unroll
    for (int n = 0; n < K1_PX; ++n) s += xt[n][t];
    rpart[(size_t)blk * CC + t] = s;
  }

  // S partial: 4x4 register tile over 32 pixels
  const int i0 = (t >> 4) * 4;
  const int j0 = (t & 15) * 4;
  float acc[4][4] = {};
#pragma unroll
  for (int n = 0; n < K1_PX; ++n) {
    const float4 av = *reinterpret_cast<const float4*>(&xt[n][i0]);
    const float4 bv = *reinterpret_cast<const float4*>(&xt[n][j0]);
    const float a[4] = {av.x, av.y, av.z, av.w};
    const float b[4] = {bv.x, bv.y, bv.z, bv.w};
#pragma unroll
    for (int ii = 0; ii < 4; ++ii)
#pragma unroll
      for (int jj = 0; jj < 4; ++jj) acc[ii][jj] += a[ii] * b[jj];
  }

  float* Sp = Spart + (size_t)blk * (CC * CC);
#pragma unroll
  for (int ii = 0; ii < 4; ++ii) {
    const float4 v4 =
        make_float4(acc[ii][0], acc[ii][1], acc[ii][2], acc[ii][3]);
    *reinterpret_cast<float4*>(&Sp[(i0 + ii) * CC + j0]) = v4;
  }
}

// ---------------------------------------------------------------------------
// kr: fold 288 partials/batch into Sf (and rf). 128 blocks, 64 elems each,
// 4-way K-split across the block's waves, coalesced loads.
// ---------------------------------------------------------------------------
__global__ __launch_bounds__(256) void kr_reduce(
    const float* __restrict__ Spart, const float* __restrict__ rpart,
    float* __restrict__ Sf, float* __restrict__ rf) {
  __shared__ float red[4][KR_ELEMS];
  const int t = threadIdx.x;
  const int blk = blockIdx.x;
  const int batch = blk >> 6;
  const int e0 = (blk & 63) * KR_ELEMS;
  const int lane = t & 63;
  const int ks = t >> 6;  // 0..3

  const float* __restrict__ Sp =
      Spart + (size_t)batch * K1_CHUNKS * (CC * CC);
  float s = 0.f;
#pragma unroll 4
  for (int k = ks * KSLICE; k < (ks + 1) * KSLICE; ++k)
    s += Sp[(size_t)k * (CC * CC) + e0 + lane];
  red[ks][lane] = s;
  __syncthreads();
  if (t < KR_ELEMS)
    Sf[batch * (CC * CC) + e0 + t] =
        red[0][t] + red[1][t] + red[2][t] + red[3][t];

  if ((blk & 63) == 0) {  // block-uniform branch; one block per batch does r
    const float* __restrict__ rp = rpart + (size_t)batch * K1_CHUNKS * CC;
    float sr = 0.f;
#pragma unroll 4
    for (int k = ks * KSLICE; k < (ks + 1) * KSLICE; ++k)
      sr += rp[(size_t)k * CC + lane];
    __syncthreads();
    red[ks][lane] = sr;
    __syncthreads();
    if (t < CC)
      rf[batch * CC + t] = red[0][t] + red[1][t] + red[2][t] + red[3][t];
  }
}

// ---------------------------------------------------------------------------
// k3: per-block redundant tiny algebra -> W_b, b_b in LDS, then apply
//     Z = X + W_b X + b_b on this block's 64-px tile. 288 blocks.
// ---------------------------------------------------------------------------
struct Alg {
  float S[CC][CC + 1];
  float Gt[CC][CI + 1];  // gw transposed
  float A[CI][CC + 1];   // pw @ S
  float M[CI][CI + 1];
  float T1[CI][CC + 1];  // (M^T tw)
  float r[CC];
  float u[CI], v[CI], t2[CI];
};

struct Smem {
  union U {
    Alg alg;                 // 46.6 KB
    float xt[CC][K3_PX + 4]; // 17.4 KB
  } u;
  float Wt[CC][CC + 4];      // Wt[inch][outch], persists algebra -> apply
  float bl[CC];
};

__global__ __launch_bounds__(256) void k3_apply(
    const float* __restrict__ x, const float* __restrict__ tw,
    const float* __restrict__ tb, const float* __restrict__ pw,
    const float* __restrict__ pb, const float* __restrict__ gw,
    const float* __restrict__ gb, const float* __restrict__ rw,
    const float* __restrict__ rb, float* __restrict__ z,
    const float* __restrict__ Sf, const float* __restrict__ rf) {
  __shared__ __align__(16) Smem sm;
  const int t = threadIdx.x;
  const int blk = blockIdx.x;
  const int batch = blk / K3_CHUNKS;
  const int chk = blk - batch * K3_CHUNKS;

  // ---- algebra (every block, redundantly; operands L2-hot)
  {
    Alg& a = sm.u.alg;
    const float* Sb = Sf + (size_t)batch * CC * CC;
    for (int idx = t; idx < CC * CC; idx += 256)
      a.S[idx >> 6][idx & 63] = Sb[idx];
    for (int idx = t; idx < CI * CC; idx += 256) {
      int c = idx >> 6, j = idx & 63;
      a.Gt[j][c] = gw[idx];
    }
    if (t < CC) a.r[t] = rf[batch * CC + t];
    __syncthreads();

    if (t < CI) {
      float s = 0.f;
      for (int i = 0; i < CC; ++i) s += gw[t * CC + i] * a.r[i];
      a.u[t] = s;
    } else if (t < 2 * CI) {
      const int k = t - CI;
      float s = 0.f;
      for (int i = 0; i < CC; ++i) s += pw[k * CC + i] * a.r[i];
      a.v[k] = s;
    }
    for (int o = t; o < CI * CC; o += 256) {  // A = pw @ S
      const int k = o >> 6, j = o & 63;
      float s = 0.f;
      for (int i = 0; i < CC; ++i) s += pw[k * CC + i] * a.S[i][j];
      a.A[k][j] = s;
    }
    __syncthreads();

    for (int o = t; o < CI * CI; o += 256) {  // M
      const int k = o >> 5, c = o & 31;
      float s = 0.f;
      for (int j = 0; j < CC; ++j) s += a.A[k][j] * a.Gt[j][c];
      s += a.v[k] * gb[c] + pb[k] * a.u[c] + (float)NPIX * pb[k] * gb[c];
      a.M[k][c] = s;
    }
    __syncthreads();

    for (int o = t; o < CI * CC; o += 256) {  // T1 = M^T tw
      const int c = o >> 6, j = o & 63;
      float s = 0.f;
      for (int k = 0; k < CI; ++k) s += a.M[k][c] * tw[k * CC + j];
      a.T1[c][j] = s;
    }
    if (t < CI) {
      float s = 0.f;
      for (int k = 0; k < CI; ++k) s += a.M[k][t] * tb[k];
      a.t2[t] = s;
    }
    __syncthreads();

    const float invN = 1.0f / (float)NPIX;
    for (int o = t; o < CC * CC; o += 256) {  // Wt = (rw @ T1)^T / N
      const int oc = o >> 6, j = o & 63;
      float s = 0.f;
      for (int c = 0; c < CI; ++c) s += rw[oc * CI + c] * a.T1[c][j];
      sm.Wt[j][oc] = s * invN;
    }
    if (t < CC) {
      float s = 0.f;
      for (int c = 0; c < CI; ++c) s += rw[t * CI + c] * a.t2[c];
      sm.bl[t] = s * invN + rb[t];
    }
  }
  __syncthreads();

  // ---- apply: Z = X + W_b X + b_b on this block's 64-px tile
  {
    const int n0 = chk * K3_PX;
    const float* __restrict__ X = x + (size_t)batch * CC * NPIX;
    float* __restrict__ Z = z + (size_t)batch * CC * NPIX;

    for (int idx = t; idx < CC * K3_PX / 4; idx += 256) {
      const int k = idx >> 4;        // channel (64px / 4 = 16 groups)
      const int n = (idx & 15) * 4;  // pixel group
      *reinterpret_cast<float4*>(&sm.u.xt[k][n]) =
          *reinterpret_cast<const float4*>(&X[(size_t)k * NPIX + n0 + n]);
    }
    __syncthreads();

    const int c0 = (t >> 5) * 8;   // 8 channels per thread
    const int m0 = (t & 31) * 2;   // 2 pixels per thread
    float acc[8][2] = {};
#pragma unroll 8
    for (int k = 0; k < CC; ++k) {
      const float2 xv = *reinterpret_cast<const float2*>(&sm.u.xt[k][m0]);
      const float4 w0 = *reinterpret_cast<const float4*>(&sm.Wt[k][c0]);
      const float4 w1 = *reinterpret_cast<const float4*>(&sm.Wt[k][c0 + 4]);
      const float wa[8] = {w0.x, w0.y, w0.z, w0.w, w1.x, w1.y, w1.z, w1.w};
#pragma unroll
      for (int cc = 0; cc < 8; ++cc) {
        acc[cc][0] += wa[cc] * xv.x;
        acc[cc][1] += wa[cc] * xv.y;
      }
    }

#pragma unroll
    for (int cc = 0; cc < 8; ++cc) {
      const int c = c0 + cc;
      const float2 xr = *reinterpret_cast<const float2*>(&sm.u.xt[c][m0]);
      const float bb2 = sm.bl[c];
      float2 o;
      o.x = acc[cc][0] + xr.x + bb2;
      o.y = acc[cc][1] + xr.y + bb2;
      *reinterpret_cast<float2*>(&Z[(size_t)c * NPIX + n0 + m0]) = o;
    }
  }
}

extern "C" void kernel_launch(void* const* d_in, const int* in_sizes, int n_in,
                              void* d_out, int out_size, void* d_ws,
                              size_t ws_size, hipStream_t stream) {
  (void)in_sizes; (void)n_in; (void)out_size; (void)ws_size;
  const float* x  = (const float*)d_in[0];
  const float* tw = (const float*)d_in[1];
  const float* tb = (const float*)d_in[2];
  const float* pw = (const float*)d_in[3];
  const float* pb = (const float*)d_in[4];
  const float* gw = (const float*)d_in[5];
  const float* gb = (const float*)d_in[6];
  const float* rw = (const float*)d_in[7];
  const float* rb = (const float*)d_in[8];
  float* z = (float*)d_out;

  float* Spart = (float*)d_ws;                          // 576*4096
  float* rpart = Spart + (size_t)K1_BLOCKS * CC * CC;   // 576*64
  float* Sf    = rpart + (size_t)K1_BLOCKS * CC;        // 2*4096
  float* rf    = Sf + (size_t)BB * CC * CC;             // 2*64

  hipLaunchKernelGGL(k1_partials, dim3(K1_BLOCKS), dim3(256), 0, stream,
                     x, Spart, rpart);
  hipLaunchKernelGGL(kr_reduce, dim3(KR_BLOCKS), dim3(256), 0, stream,
                     Spart, rpart, Sf, rf);
  hipLaunchKernelGGL(k3_apply, dim3(K3_BLOCKS), dim3(256), 0, stream,
                     x, tw, tb, pw, pb, gw, gb, rw, rb, z, Sf, rf);
}